// Round 11
// baseline (1398.024 us; speedup 1.0000x reference)
//
#include <hip/hip_runtime.h>
#include <hip/hip_fp16.h>
#include <math.h>
#include <limits.h>

#define N_NODES 50000
#define N_EDGES 800000
#define N_GRAPHS 64
#define IN_CH 128
#define EMB 64
#define POOL_CHUNK 16   // 50000 = 16 * 3125 exactly
#define CPAD64 16       // one 128B line per node: single u64 = (count<<44) | wsum_fx24
#define CNT_SHIFT 44
#define FX_SCALE 16777216.0f   // 2^24 fixed-point for edge weights (w in [0,1))
#define BM 32           // fused-kernel tile: 32 nodes (tiles are BM-aligned)
#define ECAP 2048       // LDS csr stage capacity (mean 512/tile -> never hit for random)
#define SRC_MASK 0x007FFFFF   // csr.x: low 23 bits = src byte-offset; bits 23..27 = dst&31

typedef _Float16 f16;
typedef __attribute__((ext_vector_type(8))) _Float16 half8;
typedef __attribute__((ext_vector_type(4))) float f32x4;

// ---------- init: packed counters=0, total=0, pool accumulators ----------
__global__ void init_k(unsigned long long* cnt64, int* total, int* gmax,
                       float* gsum, int* cnt) {
    int i = blockIdx.x * blockDim.x + threadIdx.x;
    if (i < N_NODES * CPAD64) cnt64[i] = 0ULL;
    if (i == 0) *total = 0;
    if (i < N_GRAPHS * EMB) { gmax[i] = INT_MIN; gsum[i] = 0.f; }
    if (i < N_GRAPHS) cnt[i] = 0;
}

// ---------- histogram: ONE packed 64-bit atomic per edge ----------
__global__ void hist_k(const int* __restrict__ dst, const float* __restrict__ w,
                       unsigned long long* cnt64, int* __restrict__ slot_in) {
    int e = blockIdx.x * blockDim.x + threadIdx.x;
    if (e >= N_EDGES) return;
    unsigned long long fx = (unsigned long long)(w[e] * FX_SCALE + 0.5f);
    unsigned long long old = atomicAdd(&cnt64[(size_t)dst[e] * CPAD64],
                                       (1ULL << CNT_SHIFT) | fx);
    slot_in[e] = (int)(old >> CNT_SHIFT);
}

// ---------- CSR range allocation: wave-scan + one atomic per wave; dinv folded ----
// One atomicAdd per 64-node group + ascending prefix => every BM-aligned tile
// owns a CONTIGUOUS csr range (fused kernels stage it in LDS).
__global__ void alloc_k(const unsigned long long* __restrict__ cnt64,
                        int* __restrict__ row_start, int* __restrict__ row_end,
                        int* total, float* __restrict__ dinv) {
    int i = blockIdx.x * blockDim.x + threadIdx.x;
    int lane = threadIdx.x & 63;
    unsigned long long v = (i < N_NODES) ? cnt64[(size_t)i * CPAD64] : 0ULL;
    int c = (int)(v >> CNT_SHIFT);
    int inc = c;
    for (int off = 1; off < 64; off <<= 1) {
        int t = __shfl_up(inc, off);
        if (lane >= off) inc += t;
    }
    int base;
    if (lane == 63) base = atomicAdd(total, inc);
    base = __shfl(base, 63);
    int excl = base + inc - c;
    if (i < N_NODES) {
        row_start[i] = excl;
        row_end[i] = excl + c;
        float degw = (float)(v & ((1ULL << CNT_SHIFT) - 1)) * (1.0f / FX_SCALE);
        float d = 1.0f + degw;  // + self-loop weight 1
        dinv[i] = d > 0.f ? rsqrtf(d) : 0.f;
    }
}

// ---------- scatter edges into CSR slots (atomic-free) ----------
// csr.x = src*EMB*2 (byte offset, 23 bits) | (dst tile-local index << 23);
// csr.y = raw w. The packed dst enables edge-parallel aggregation.
__global__ void scatter_k(const int* __restrict__ src, const int* __restrict__ dst,
                          const float* __restrict__ w, const int* __restrict__ slot_in,
                          const int* __restrict__ row_start, int2* __restrict__ csr) {
    int e = blockIdx.x * blockDim.x + threadIdx.x;
    if (e >= N_EDGES) return;
    int d = dst[e];
    int slot = row_start[d] + slot_in[e];
    csr[slot] = make_int2((src[e] * (EMB * 2)) | ((d & (BM - 1)) << 23),
                          __float_as_int(w[e]));
}

// ---------- fallback (eTot > ECAP, never hit for random data): node-parallel ----------
__device__ __forceinline__ float agg_row_g(const char* hsb, const int2* __restrict__ csr,
                                           int e, int end, float acc) {
    for (; e < end; ++e) {
        int2 r = csr[e];
        acc += __int_as_float(r.y) *
               __half2float(*(const __half*)(hsb + (r.x & SRC_MASK)));
    }
    return acc;
}

// ---------- edge-parallel accumulate into LDS Ho[dstLocal][lane] ----------
// All 8 waves stream the staged edge list: every gather in the block is
// independent (~64 in flight vs 8 with node-ownership). ds_add_f32 is
// bank-conflict-free (lane -> bank) and contention across waves is rare.
__device__ __forceinline__ void edge_parallel_acc(const char* hsb, const int2* Ecsr,
                                                  int eTot, float* Ho,
                                                  int wv, int lane) {
    for (int base = wv * 8; base < eTot; base += 64) {
        int n = eTot - base; if (n > 8) n = 8;
        if (n == 8) {
            int2 r[8];
#pragma unroll
            for (int j = 0; j < 8; ++j) r[j] = Ecsr[base + j];
            __half v[8];
#pragma unroll
            for (int j = 0; j < 8; ++j)
                v[j] = *(const __half*)(hsb + (r[j].x & SRC_MASK));
#pragma unroll
            for (int j = 0; j < 8; ++j) {
                int dl = ((unsigned)r[j].x) >> 23;
                atomicAdd(&Ho[dl * EMB + lane],
                          __int_as_float(r[j].y) * __half2float(v[j]));
            }
        } else {
            for (int j = 0; j < n; ++j) {
                int2 r = Ecsr[base + j];
                int dl = ((unsigned)r.x) >> 23;
                atomicAdd(&Ho[dl * EMB + lane],
                          __int_as_float(r.y) *
                          __half2float(*(const __half*)(hsb + (r.x & SRC_MASK))));
            }
        }
    }
}

// ---------- hs = dinv * (A @ W) via MFMA 16x16x32 f16 (layer 0, fp32 input) ----------
template<int K, bool HALF_IN>
__global__ __launch_bounds__(256) void gemm_k(const void* __restrict__ A_,
                                              const float* __restrict__ W,
                                              const float* __restrict__ dinv,
                                              __half* __restrict__ out) {
    constexpr int LDK = K + 8;
    __shared__ __align__(16) f16 Al[64 * LDK];
    __shared__ __align__(16) f16 Wt[EMB * LDK];   // Wt[n][k]
    int tid = threadIdx.x;
    long rowBase = (long)blockIdx.x * 64;
    int validRows = (int)min((long)64, (long)N_NODES - rowBase);

    if constexpr (HALF_IN) {
        const __half* Ah = (const __half*)A_ + rowBase * K;
        constexpr int CH = K / 8;
        for (int i = tid; i < validRows * CH; i += 256) {
            int r = i / CH, c = i % CH;
            uint4 v = *(const uint4*)(Ah + (long)r * K + c * 8);
            *(uint4*)&Al[r * LDK + c * 8] = v;
        }
    } else {
        const float* Af = (const float*)A_;
        constexpr int CH = K / 4;
        for (int i = tid; i < validRows * CH; i += 256) {
            int r = i / CH, c = i % CH;
            float4 v = *(const float4*)(Af + (rowBase + r) * K + c * 4);
            __half2 p0 = __floats2half2_rn(v.x, v.y);
            __half2 p1 = __floats2half2_rn(v.z, v.w);
            uint2 u = make_uint2(*(unsigned int*)&p0, *(unsigned int*)&p1);
            *(uint2*)&Al[r * LDK + c * 4] = u;
        }
    }
    {   // zero-fill invalid rows (last block only)
        constexpr int CZ = K / 8;
        for (int i = tid + validRows * CZ; i < 64 * CZ; i += 256) {
            int r = i / CZ, c = i % CZ;
            *(uint4*)&Al[r * LDK + c * 8] = make_uint4(0, 0, 0, 0);
        }
    }
    {   // stage W transposed fp32 -> fp16
        const float4* Wg = (const float4*)W;
        for (int i = tid; i < K * (EMB / 4); i += 256) {
            int k = i >> 4, nq = i & 15;
            float4 v = Wg[i];
            Wt[(4 * nq + 0) * LDK + k] = (f16)v.x;
            Wt[(4 * nq + 1) * LDK + k] = (f16)v.y;
            Wt[(4 * nq + 2) * LDK + k] = (f16)v.z;
            Wt[(4 * nq + 3) * LDK + k] = (f16)v.w;
        }
    }
    __syncthreads();

    int wv = tid >> 6, lane = tid & 63;
    int l15 = lane & 15, kg = (lane >> 4) * 8;
    const f16* Ap = &Al[(wv * 16 + l15) * LDK + kg];
    const f16* Bp = &Wt[l15 * LDK + kg];
    f32x4 acc0 = {0.f, 0.f, 0.f, 0.f};
    f32x4 acc1 = acc0, acc2 = acc0, acc3 = acc0;
#pragma unroll
    for (int ks = 0; ks < K / 32; ++ks) {
        int k0 = ks * 32;
        half8 a  = *(const half8*)(Ap + k0);
        half8 b0 = *(const half8*)(Bp + k0);
        half8 b1 = *(const half8*)(Bp + 16 * LDK + k0);
        half8 b2 = *(const half8*)(Bp + 32 * LDK + k0);
        half8 b3 = *(const half8*)(Bp + 48 * LDK + k0);
        acc0 = __builtin_amdgcn_mfma_f32_16x16x32_f16(a, b0, acc0, 0, 0, 0);
        acc1 = __builtin_amdgcn_mfma_f32_16x16x32_f16(a, b1, acc1, 0, 0, 0);
        acc2 = __builtin_amdgcn_mfma_f32_16x16x32_f16(a, b2, acc2, 0, 0, 0);
        acc3 = __builtin_amdgcn_mfma_f32_16x16x32_f16(a, b3, acc3, 0, 0, 0);
    }
    int orow = wv * 16 + (lane >> 4) * 4;
#pragma unroll
    for (int i = 0; i < 4; ++i) {
        long row = rowBase + orow + i;
        if (row >= N_NODES) break;
        float dv = dinv[row];
        __half* op = &out[row * EMB + l15];
        op[0]  = __float2half(dv * acc0[i]);
        op[16] = __float2half(dv * acc1[i]);
        op[32] = __float2half(dv * acc2[i]);
        op[48] = __float2half(dv * acc3[i]);
    }
}

// ---------- FUSED agg(layer l) + gemm(layer l+1): edge-parallel agg ----------
__global__ __launch_bounds__(512) void agg_gemm_k(const __half* __restrict__ hs_in,
                                                  const int2* __restrict__ csr,
                                                  const int* __restrict__ row_start,
                                                  const int* __restrict__ row_end,
                                                  const float* __restrict__ dinv,
                                                  const float* __restrict__ b,
                                                  const float* __restrict__ W,
                                                  __half* __restrict__ hs_out) {
    constexpr int K = EMB;       // 64
    constexpr int LDK = K + 8;   // 72
    __shared__ __align__(16) int2 Ecsr[ECAP];
    __shared__ float Ho[BM * EMB];           // fp32 accumulator (ds_add_f32)
    __shared__ __align__(16) f16 Ao[BM * LDK];
    __shared__ __align__(16) f16 Wt[EMB * LDK];
    int tid = threadIdx.x;
    int wv = tid >> 6, lane = tid & 63;
    long tileBase = (long)blockIdx.x * BM;
    int validRows = (int)min((long)BM, (long)N_NODES - tileBase);

    {   // stage W transposed fp32 -> fp16 (Wt[n][k])
        const float4* Wg = (const float4*)W;
        for (int i = tid; i < K * (EMB / 4); i += 512) {
            int k = i >> 4, nq = i & 15;
            float4 v = Wg[i];
            Wt[(4 * nq + 0) * LDK + k] = (f16)v.x;
            Wt[(4 * nq + 1) * LDK + k] = (f16)v.y;
            Wt[(4 * nq + 2) * LDK + k] = (f16)v.z;
            Wt[(4 * nq + 3) * LDK + k] = (f16)v.w;
        }
    }
    int eBeg = row_start[tileBase];
    int eTot = row_end[tileBase + validRows - 1] - eBeg;
    bool staged = (eTot <= ECAP);
    if (staged) {   // coalesced bulk load of the tile's whole csr slice
        for (int i = tid; i < eTot; i += 512) Ecsr[i] = csr[eBeg + i];
    }
    {   // self-term init of Ho (owner wave: nodes wv*4..wv*4+3)
        for (int i = 0; i < 4; ++i) {
            long node = tileBase + wv * 4 + i;
            if (node >= N_NODES) break;
            Ho[(wv * 4 + i) * EMB + lane] = __half2float(hs_in[node * EMB + lane]);
        }
    }
    __syncthreads();
    const char* hsb = (const char*)hs_in + (size_t)(lane * 2);
    if (staged) {
        edge_parallel_acc(hsb, Ecsr, eTot, Ho, wv, lane);
    } else {   // fallback: node-parallel over global csr (owner-exclusive writes)
        for (int i = 0; i < 4; ++i) {
            long node = tileBase + wv * 4 + i;
            if (node >= N_NODES) break;
            float acc = agg_row_g(hsb, csr, row_start[node], row_end[node], 0.f);
            Ho[(wv * 4 + i) * EMB + lane] += acc;
        }
    }
    __syncthreads();
    {   // finish: tanh(dinv * sum + b) -> fp16 A-tile
        float bl = b[lane];
        for (int i = 0; i < 4; ++i) {
            long node = tileBase + wv * 4 + i;
            if (node >= N_NODES) break;
            float o = tanhf(dinv[node] * Ho[(wv * 4 + i) * EMB + lane] + bl);
            Ao[(wv * 4 + i) * LDK + lane] = (f16)o;
        }
    }
    if (validRows < BM) {   // zero-fill invalid rows (tail block only)
        for (int i = tid; i < (BM - validRows) * (K / 8); i += 512) {
            int r = validRows + i / (K / 8), c = i % (K / 8);
            *(uint4*)&Ao[r * LDK + c * 8] = make_uint4(0, 0, 0, 0);
        }
    }
    __syncthreads();
    {   // MFMA 32x64 @ 64x64; one 16x16 tile per wave
        int l15 = lane & 15, kg = (lane >> 4) * 8;
        int r0 = (wv & 1) * 16;
        int c0 = (wv >> 1) * 16;
        const f16* Ap = &Ao[(r0 + l15) * LDK + kg];
        const f16* Bp = &Wt[(c0 + l15) * LDK + kg];
        f32x4 acc = {0.f, 0.f, 0.f, 0.f};
#pragma unroll
        for (int ks = 0; ks < K / 32; ++ks) {
            int k0 = ks * 32;
            half8 a  = *(const half8*)(Ap + k0);
            half8 bb = *(const half8*)(Bp + k0);
            acc = __builtin_amdgcn_mfma_f32_16x16x32_f16(a, bb, acc, 0, 0, 0);
        }
        int orow = r0 + (lane >> 4) * 4;
#pragma unroll
        for (int i = 0; i < 4; ++i) {
            long row = tileBase + orow + i;
            if (row >= N_NODES) break;
            float dv = dinv[row];
            hs_out[row * EMB + c0 + l15] = __float2half(dv * acc[i]);
        }
    }
}

// ---------- pooling helpers ----------
__device__ inline int f2ord(float x) {
    int bb = __float_as_int(x);
    return bb >= 0 ? bb : (bb ^ 0x7fffffff);
}
__device__ inline float ord2f(int k) {
    return __int_as_float(k >= 0 ? k : (k ^ 0x7fffffff));
}

// ---------- FUSED agg(layer 3) + pool: edge-parallel agg ----------
__global__ __launch_bounds__(512) void agg_pool_k(const __half* __restrict__ hs_in,
                                                  const int2* __restrict__ csr,
                                                  const int* __restrict__ row_start,
                                                  const int* __restrict__ row_end,
                                                  const float* __restrict__ dinv,
                                                  const float* __restrict__ b,
                                                  const int* __restrict__ batch,
                                                  int* gmax, float* gsum, int* cnt) {
    __shared__ __align__(16) int2 Ecsr[ECAP];
    __shared__ float Ho[BM * EMB];
    int tid = threadIdx.x;
    int wv = tid >> 6, lane = tid & 63;
    long tileBase = (long)blockIdx.x * BM;
    int validRows = (int)min((long)BM, (long)N_NODES - tileBase);

    int eBeg = row_start[tileBase];
    int eTot = row_end[tileBase + validRows - 1] - eBeg;
    bool staged = (eTot <= ECAP);
    if (staged) {
        for (int i = tid; i < eTot; i += 512) Ecsr[i] = csr[eBeg + i];
    }
    {   // self-term init
        for (int i = 0; i < 4; ++i) {
            long node = tileBase + wv * 4 + i;
            if (node >= N_NODES) break;
            Ho[(wv * 4 + i) * EMB + lane] = __half2float(hs_in[node * EMB + lane]);
        }
    }
    __syncthreads();
    const char* hsb = (const char*)hs_in + (size_t)(lane * 2);
    if (staged) {
        edge_parallel_acc(hsb, Ecsr, eTot, Ho, wv, lane);
    } else {
        for (int i = 0; i < 4; ++i) {
            long node = tileBase + wv * 4 + i;
            if (node >= N_NODES) break;
            float acc = agg_row_g(hsb, csr, row_start[node], row_end[node], 0.f);
            Ho[(wv * 4 + i) * EMB + lane] += acc;
        }
    }
    __syncthreads();
    {   // finish: tanh in place
        float bl = b[lane];
        for (int i = 0; i < 4; ++i) {
            long node = tileBase + wv * 4 + i;
            if (node >= N_NODES) break;
            Ho[(wv * 4 + i) * EMB + lane] =
                tanhf(dinv[node] * Ho[(wv * 4 + i) * EMB + lane] + bl);
        }
    }
    __syncthreads();
    if (wv < BM / POOL_CHUNK) {   // waves 0-1 pool the two 16-node chunks
        long start = tileBase + wv * POOL_CHUNK;
        if (start >= N_NODES) return;   // 50000 % 16 == 0 -> full chunks when valid
        int bsel = (lane < POOL_CHUNK) ? batch[start + lane] : 0;
        float v[POOL_CHUNK];
#pragma unroll
        for (int i = 0; i < POOL_CHUNK; ++i)
            v[i] = Ho[(wv * POOL_CHUNK + i) * EMB + lane];
        int curg = __shfl(bsel, 0);
        float mx = -INFINITY, sm = 0.f;
        int ct = 0;
#pragma unroll
        for (int i = 0; i < POOL_CHUNK; ++i) {
            int g = __shfl(bsel, i);
            if (g != curg) {
                atomicMax(&gmax[curg * EMB + lane], f2ord(mx));
                atomicAdd(&gsum[curg * EMB + lane], sm);
                if (lane == 0) atomicAdd(&cnt[curg], ct);
                curg = g; mx = -INFINITY; sm = 0.f; ct = 0;
            }
            mx = fmaxf(mx, v[i]);
            sm += v[i];
            ++ct;
        }
        atomicMax(&gmax[curg * EMB + lane], f2ord(mx));
        atomicAdd(&gsum[curg * EMB + lane], sm);
        if (lane == 0) atomicAdd(&cnt[curg], ct);
    }
}

__global__ void final_k(const int* __restrict__ gmax, const float* __restrict__ gsum,
                        const int* __restrict__ cnt, const float* __restrict__ Wout,
                        const float* __restrict__ bout, float* __restrict__ out) {
    int g = threadIdx.x;
    if (g >= N_GRAPHS) return;
    float c = fmaxf((float)cnt[g], 1.0f);
    float acc = bout[0];
    for (int ch = 0; ch < EMB; ++ch) {
        acc += ord2f(gmax[g * EMB + ch]) * Wout[ch]
             + (gsum[g * EMB + ch] / c) * Wout[EMB + ch];
    }
    out[g] = acc;
}

extern "C" void kernel_launch(void* const* d_in, const int* in_sizes, int n_in,
                              void* d_out, int out_size, void* d_ws, size_t ws_size,
                              hipStream_t stream) {
    const float* x         = (const float*)d_in[0];
    const int*   edge_idx  = (const int*)d_in[1];
    const float* edge_attr = (const float*)d_in[2];
    const int*   batch     = (const int*)d_in[3];
    const float* W0 = (const float*)d_in[4];
    const float* b0 = (const float*)d_in[5];
    const float* W1 = (const float*)d_in[6];
    const float* b1 = (const float*)d_in[7];
    const float* W2 = (const float*)d_in[8];
    const float* b2 = (const float*)d_in[9];
    const float* W3 = (const float*)d_in[10];
    const float* b3 = (const float*)d_in[11];
    const float* Wout = (const float*)d_in[12];
    const float* bout = (const float*)d_in[13];
    float* out = (float*)d_out;

    const int* src = edge_idx;            // edge_index[0]
    const int* dst = edge_idx + N_EDGES;  // edge_index[1]

    // workspace layout (~33 MB)
    char* ws = (char*)d_ws;
    float*  dinv      = (float*)ws;  ws += (size_t)N_NODES * sizeof(float);
    unsigned long long* cnt64 = (unsigned long long*)ws;
    ws += (size_t)N_NODES * CPAD64 * sizeof(unsigned long long);
    int*    row_start = (int*)ws;    ws += (size_t)N_NODES * sizeof(int);
    int*    row_end   = (int*)ws;    ws += (size_t)N_NODES * sizeof(int);
    int*    slot_in   = (int*)ws;    ws += (size_t)N_EDGES * sizeof(int);
    int*    total     = (int*)ws;    ws += 4 * sizeof(int);  // keep 16B alignment
    int2*   csr       = (int2*)ws;   ws += (size_t)N_EDGES * sizeof(int2);
    __half* bufL      = (__half*)ws; ws += (size_t)N_NODES * EMB * sizeof(__half);
    __half* bufM      = (__half*)ws; ws += (size_t)N_NODES * EMB * sizeof(__half);
    int*    gmax      = (int*)ws;    ws += N_GRAPHS * EMB * sizeof(int);
    float*  gsum      = (float*)ws;  ws += N_GRAPHS * EMB * sizeof(float);
    int*    cnt       = (int*)ws;    ws += N_GRAPHS * sizeof(int);

    const int nodeB  = (N_NODES + 255) / 256;
    const int edgeB  = (N_EDGES + 255) / 256;
    const int gemm0B = (N_NODES + 63) / 64;      // 782 blocks, 64-node tiles
    const int fuseB  = (N_NODES + BM - 1) / BM;  // 1563 blocks, 32-node tiles
    const int initB  = (N_NODES * CPAD64 + 255) / 256;

    // CSR precompute (norm fully folded; count+weighted-degree via ONE 64b atomic)
    init_k<<<initB, 256, 0, stream>>>(cnt64, total, gmax, gsum, cnt);
    hist_k<<<edgeB, 256, 0, stream>>>(dst, edge_attr, cnt64, slot_in);
    alloc_k<<<nodeB, 256, 0, stream>>>(cnt64, row_start, row_end, total, dinv);
    scatter_k<<<edgeB, 256, 0, stream>>>(src, dst, edge_attr, slot_in, row_start, csr);

    // layer pipeline: gemm0, then fused agg_l+gemm_{l+1}, then fused agg3+pool
    gemm_k<IN_CH, false><<<gemm0B, 256, 0, stream>>>(x, W0, dinv, bufL);
    agg_gemm_k<<<fuseB, 512, 0, stream>>>(bufL, csr, row_start, row_end, dinv, b0, W1, bufM);
    agg_gemm_k<<<fuseB, 512, 0, stream>>>(bufM, csr, row_start, row_end, dinv, b1, W2, bufL);
    agg_gemm_k<<<fuseB, 512, 0, stream>>>(bufL, csr, row_start, row_end, dinv, b2, W3, bufM);
    agg_pool_k<<<fuseB, 512, 0, stream>>>(bufM, csr, row_start, row_end, dinv, b3,
                                          batch, gmax, gsum, cnt);
    final_k<<<1, 64, 0, stream>>>(gmax, gsum, cnt, Wout, bout, out);
}

// Round 12
// 346.964 us; speedup vs baseline: 4.0293x; 4.0293x over previous
//
#include <hip/hip_runtime.h>
#include <hip/hip_fp16.h>
#include <math.h>
#include <limits.h>

#define N_NODES 50000
#define N_EDGES 800000
#define N_GRAPHS 64
#define IN_CH 128
#define EMB 64
#define POOL_CHUNK 16   // 50000 = 16 * 3125 exactly
#define CPAD64 16       // one 128B line per node: single u64 = (count<<44) | wsum_fx24
#define CNT_SHIFT 44
#define FX_SCALE 16777216.0f   // 2^24 fixed-point for edge weights (w in [0,1))
#define BM 32           // fused-kernel tile: 32 nodes (tiles are BM-aligned)
#define ECAP 2048       // LDS csr stage capacity, PADDED (mean 512+224 pad max typical)
#define SRC_MASK 0x007FFFFF   // csr.x: low 23 bits = src byte-offset; bits 23..27 = dst&31

typedef _Float16 f16;
typedef __attribute__((ext_vector_type(8))) _Float16 half8;
typedef __attribute__((ext_vector_type(4))) float f32x4;

// ---------- init: packed counters=0, total=0, pool accumulators ----------
__global__ void init_k(unsigned long long* cnt64, int* total, int* gmax,
                       float* gsum, int* cnt) {
    int i = blockIdx.x * blockDim.x + threadIdx.x;
    if (i < N_NODES * CPAD64) cnt64[i] = 0ULL;
    if (i == 0) *total = 0;
    if (i < N_GRAPHS * EMB) { gmax[i] = INT_MIN; gsum[i] = 0.f; }
    if (i < N_GRAPHS) cnt[i] = 0;
}

// ---------- histogram: ONE packed 64-bit atomic per edge ----------
__global__ void hist_k(const int* __restrict__ dst, const float* __restrict__ w,
                       unsigned long long* cnt64, int* __restrict__ slot_in) {
    int e = blockIdx.x * blockDim.x + threadIdx.x;
    if (e >= N_EDGES) return;
    unsigned long long fx = (unsigned long long)(w[e] * FX_SCALE + 0.5f);
    unsigned long long old = atomicAdd(&cnt64[(size_t)dst[e] * CPAD64],
                                       (1ULL << CNT_SHIFT) | fx);
    slot_in[e] = (int)(old >> CNT_SHIFT);
}

// ---------- CSR range allocation: wave-scan + one atomic per wave; dinv folded ----
// One atomicAdd per 64-node group + ascending prefix => every BM-aligned tile
// owns a CONTIGUOUS csr range (fused kernels stage it in LDS).
__global__ void alloc_k(const unsigned long long* __restrict__ cnt64,
                        int* __restrict__ row_start, int* __restrict__ row_end,
                        int* total, float* __restrict__ dinv) {
    int i = blockIdx.x * blockDim.x + threadIdx.x;
    int lane = threadIdx.x & 63;
    unsigned long long v = (i < N_NODES) ? cnt64[(size_t)i * CPAD64] : 0ULL;
    int c = (int)(v >> CNT_SHIFT);
    int inc = c;
    for (int off = 1; off < 64; off <<= 1) {
        int t = __shfl_up(inc, off);
        if (lane >= off) inc += t;
    }
    int base;
    if (lane == 63) base = atomicAdd(total, inc);
    base = __shfl(base, 63);
    int excl = base + inc - c;
    if (i < N_NODES) {
        row_start[i] = excl;
        row_end[i] = excl + c;
        float degw = (float)(v & ((1ULL << CNT_SHIFT) - 1)) * (1.0f / FX_SCALE);
        float d = 1.0f + degw;  // + self-loop weight 1
        dinv[i] = d > 0.f ? rsqrtf(d) : 0.f;
    }
}

// ---------- scatter edges into CSR slots (atomic-free) ----------
// csr.x = src*EMB*2 (byte offset, 23 bits) | (dst tile-local index << 23);
// csr.y = raw w. dl enables the padded LDS staging map.
__global__ void scatter_k(const int* __restrict__ src, const int* __restrict__ dst,
                          const float* __restrict__ w, const int* __restrict__ slot_in,
                          const int* __restrict__ row_start, int2* __restrict__ csr) {
    int e = blockIdx.x * blockDim.x + threadIdx.x;
    if (e >= N_EDGES) return;
    int d = dst[e];
    int slot = row_start[d] + slot_in[e];
    csr[slot] = make_int2((src[e] * (EMB * 2)) | ((d & (BM - 1)) << 23),
                          __float_as_int(w[e]));
}

// ---------- fallback (padded slice > ECAP; never hit for random): node-serial ----------
__device__ __forceinline__ float agg_row_g(const char* hsb, const int2* __restrict__ csr,
                                           int e, int end, float acc) {
    for (; e < end; ++e) {
        int2 r = csr[e];
        acc += __int_as_float(r.y) *
               __half2float(*(const __half*)(hsb + (r.x & SRC_MASK)));
    }
    return acc;
}

// ---------- 4-chain interleaved aggregation (register accumulators) ----------
// Each wave owns 4 nodes; per m-iteration all 4 nodes' 8-edge batches issue
// (32 gathers outstanding) before any FMA waits. Edge lists are 8-PADDED in
// LDS (pad w=0 -> exact +0.0f) so every batch is full and wave-uniform.
// All register arrays statically indexed (full unroll).
__device__ __forceinline__ void agg_chains4(const char* hsb, const int2* Ecsr,
                                            const int* bs, const int* nb,
                                            float* acc) {
    int Mmax = max(max(nb[0], nb[1]), max(nb[2], nb[3]));
    for (int m = 0; m < Mmax; ++m) {
        int2 r[4][8];
        __half v[4][8];
#pragma unroll
        for (int i = 0; i < 4; ++i) {
            if (m < nb[i]) {
                const int2* p = &Ecsr[bs[i] + m * 8];
#pragma unroll
                for (int j = 0; j < 8; ++j) r[i][j] = p[j];
#pragma unroll
                for (int j = 0; j < 8; ++j)
                    v[i][j] = *(const __half*)(hsb + (r[i][j].x & SRC_MASK));
            }
        }
#pragma unroll
        for (int i = 0; i < 4; ++i) {
            if (m < nb[i]) {
#pragma unroll
                for (int j = 0; j < 8; ++j)
                    acc[i] += __int_as_float(r[i][j].y) * __half2float(v[i][j]);
            }
        }
    }
}

// ---------- padded-staging prologue (shared by both fused kernels) ----------
// Wave 0: 32-lane shfl scan of real/padded degrees -> RealB/PadB bases.
// Then zero-fill padded region, then scatter real edges to padded slots.
#define STAGE_PADDED()                                                          \
    if (wv == 0) {                                                              \
        int j = lane;                                                           \
        int deg = 0;                                                            \
        if (j < BM) {                                                           \
            long node = tileBase + j;                                           \
            if (node < N_NODES) deg = row_end[node] - row_start[node];          \
        }                                                                       \
        int pd = (deg + 7) & ~7;                                                \
        int incd = deg, incp = pd;                                              \
        for (int off = 1; off < 32; off <<= 1) {                                \
            int t = __shfl_up(incd, off);  if (lane >= off) incd += t;          \
            int t2 = __shfl_up(incp, off); if (lane >= off) incp += t2;         \
        }                                                                       \
        if (j < BM) { RealB[j] = incd - deg; PadB[j] = incp - pd; }             \
        if (j == BM - 1) { PadB[BM] = incp; realTot = incd; }                   \
    }                                                                           \
    __syncthreads();                                                            \
    int eTot = realTot;                                                         \
    int padTot = PadB[BM];                                                      \
    bool staged = (padTot <= ECAP);                                             \
    if (staged) {                                                               \
        for (int i = tid; i < padTot; i += 512) Ecsr[i] = make_int2(0, 0);      \
    }                                                                           \
    __syncthreads();                                                            \
    if (staged) {                                                               \
        int eBeg = row_start[tileBase];                                         \
        for (int i = tid; i < eTot; i += 512) {                                 \
            int2 r = csr[eBeg + i];                                             \
            int dl = ((unsigned)r.x) >> 23;                                     \
            Ecsr[PadB[dl] + (i - RealB[dl])] = r;                               \
        }                                                                       \
    }

// ---------- hs = dinv * (A @ W) via MFMA 16x16x32 f16 (layer 0, fp32 input) ----------
template<int K, bool HALF_IN>
__global__ __launch_bounds__(256) void gemm_k(const void* __restrict__ A_,
                                              const float* __restrict__ W,
                                              const float* __restrict__ dinv,
                                              __half* __restrict__ out) {
    constexpr int LDK = K + 8;
    __shared__ __align__(16) f16 Al[64 * LDK];
    __shared__ __align__(16) f16 Wt[EMB * LDK];   // Wt[n][k]
    int tid = threadIdx.x;
    long rowBase = (long)blockIdx.x * 64;
    int validRows = (int)min((long)64, (long)N_NODES - rowBase);

    if constexpr (HALF_IN) {
        const __half* Ah = (const __half*)A_ + rowBase * K;
        constexpr int CH = K / 8;
        for (int i = tid; i < validRows * CH; i += 256) {
            int r = i / CH, c = i % CH;
            uint4 v = *(const uint4*)(Ah + (long)r * K + c * 8);
            *(uint4*)&Al[r * LDK + c * 8] = v;
        }
    } else {
        const float* Af = (const float*)A_;
        constexpr int CH = K / 4;
        for (int i = tid; i < validRows * CH; i += 256) {
            int r = i / CH, c = i % CH;
            float4 v = *(const float4*)(Af + (rowBase + r) * K + c * 4);
            __half2 p0 = __floats2half2_rn(v.x, v.y);
            __half2 p1 = __floats2half2_rn(v.z, v.w);
            uint2 u = make_uint2(*(unsigned int*)&p0, *(unsigned int*)&p1);
            *(uint2*)&Al[r * LDK + c * 4] = u;
        }
    }
    {   // zero-fill invalid rows (last block only)
        constexpr int CZ = K / 8;
        for (int i = tid + validRows * CZ; i < 64 * CZ; i += 256) {
            int r = i / CZ, c = i % CZ;
            *(uint4*)&Al[r * LDK + c * 8] = make_uint4(0, 0, 0, 0);
        }
    }
    {   // stage W transposed fp32 -> fp16
        const float4* Wg = (const float4*)W;
        for (int i = tid; i < K * (EMB / 4); i += 256) {
            int k = i >> 4, nq = i & 15;
            float4 v = Wg[i];
            Wt[(4 * nq + 0) * LDK + k] = (f16)v.x;
            Wt[(4 * nq + 1) * LDK + k] = (f16)v.y;
            Wt[(4 * nq + 2) * LDK + k] = (f16)v.z;
            Wt[(4 * nq + 3) * LDK + k] = (f16)v.w;
        }
    }
    __syncthreads();

    int wv = tid >> 6, lane = tid & 63;
    int l15 = lane & 15, kg = (lane >> 4) * 8;
    const f16* Ap = &Al[(wv * 16 + l15) * LDK + kg];
    const f16* Bp = &Wt[l15 * LDK + kg];
    f32x4 acc0 = {0.f, 0.f, 0.f, 0.f};
    f32x4 acc1 = acc0, acc2 = acc0, acc3 = acc0;
#pragma unroll
    for (int ks = 0; ks < K / 32; ++ks) {
        int k0 = ks * 32;
        half8 a  = *(const half8*)(Ap + k0);
        half8 b0 = *(const half8*)(Bp + k0);
        half8 b1 = *(const half8*)(Bp + 16 * LDK + k0);
        half8 b2 = *(const half8*)(Bp + 32 * LDK + k0);
        half8 b3 = *(const half8*)(Bp + 48 * LDK + k0);
        acc0 = __builtin_amdgcn_mfma_f32_16x16x32_f16(a, b0, acc0, 0, 0, 0);
        acc1 = __builtin_amdgcn_mfma_f32_16x16x32_f16(a, b1, acc1, 0, 0, 0);
        acc2 = __builtin_amdgcn_mfma_f32_16x16x32_f16(a, b2, acc2, 0, 0, 0);
        acc3 = __builtin_amdgcn_mfma_f32_16x16x32_f16(a, b3, acc3, 0, 0, 0);
    }
    int orow = wv * 16 + (lane >> 4) * 4;
#pragma unroll
    for (int i = 0; i < 4; ++i) {
        long row = rowBase + orow + i;
        if (row >= N_NODES) break;
        float dv = dinv[row];
        __half* op = &out[row * EMB + l15];
        op[0]  = __float2half(dv * acc0[i]);
        op[16] = __float2half(dv * acc1[i]);
        op[32] = __float2half(dv * acc2[i]);
        op[48] = __float2half(dv * acc3[i]);
    }
}

// ---------- FUSED agg(layer l) + gemm(layer l+1): 4-chain interleaved agg ----------
__global__ __launch_bounds__(512) void agg_gemm_k(const __half* __restrict__ hs_in,
                                                  const int2* __restrict__ csr,
                                                  const int* __restrict__ row_start,
                                                  const int* __restrict__ row_end,
                                                  const float* __restrict__ dinv,
                                                  const float* __restrict__ b,
                                                  const float* __restrict__ W,
                                                  __half* __restrict__ hs_out) {
    constexpr int K = EMB;       // 64
    constexpr int LDK = K + 8;   // 72
    __shared__ __align__(16) int2 Ecsr[ECAP];
    __shared__ __align__(16) f16 Ao[BM * LDK];
    __shared__ __align__(16) f16 Wt[EMB * LDK];
    __shared__ int PadB[BM + 1], RealB[BM];
    __shared__ int realTot;
    int tid = threadIdx.x;
    int wv = tid >> 6, lane = tid & 63;
    long tileBase = (long)blockIdx.x * BM;
    int validRows = (int)min((long)BM, (long)N_NODES - tileBase);

    {   // stage W transposed fp32 -> fp16 (Wt[n][k])
        const float4* Wg = (const float4*)W;
        for (int i = tid; i < K * (EMB / 4); i += 512) {
            int k = i >> 4, nq = i & 15;
            float4 v = Wg[i];
            Wt[(4 * nq + 0) * LDK + k] = (f16)v.x;
            Wt[(4 * nq + 1) * LDK + k] = (f16)v.y;
            Wt[(4 * nq + 2) * LDK + k] = (f16)v.z;
            Wt[(4 * nq + 3) * LDK + k] = (f16)v.w;
        }
    }
    STAGE_PADDED();
    __syncthreads();

    const char* hsb = (const char*)hs_in + (size_t)(lane * 2);
    float acc[4];
    int bs[4], nb[4];
#pragma unroll
    for (int i = 0; i < 4; ++i) {
        long node = tileBase + wv * 4 + i;
        bool valid = node < N_NODES;
        acc[i] = valid ? __half2float(hs_in[node * EMB + lane]) : 0.f;   // self term
        int idx = wv * 4 + i;
        bs[i] = PadB[idx];
        nb[i] = staged ? ((PadB[idx + 1] - PadB[idx]) >> 3) : 0;
    }
    if (staged) {
        agg_chains4(hsb, Ecsr, bs, nb, acc);
    } else {   // fallback: node-serial over global csr
#pragma unroll
        for (int i = 0; i < 4; ++i) {
            long node = tileBase + wv * 4 + i;
            if (node >= N_NODES) break;
            acc[i] = agg_row_g(hsb, csr, row_start[node], row_end[node], acc[i]);
        }
    }
    {   // finish: tanh(dinv*sum + b) -> fp16 A-tile
        float bl = b[lane];
#pragma unroll
        for (int i = 0; i < 4; ++i) {
            long node = tileBase + wv * 4 + i;
            if (node >= N_NODES) break;
            float o = tanhf(dinv[node] * acc[i] + bl);
            Ao[(wv * 4 + i) * LDK + lane] = (f16)o;
        }
    }
    if (validRows < BM) {   // zero-fill invalid rows (tail block only)
        for (int i = tid; i < (BM - validRows) * (K / 8); i += 512) {
            int r = validRows + i / (K / 8), c = i % (K / 8);
            *(uint4*)&Ao[r * LDK + c * 8] = make_uint4(0, 0, 0, 0);
        }
    }
    __syncthreads();
    {   // MFMA 32x64 @ 64x64; one 16x16 tile per wave
        int l15 = lane & 15, kg = (lane >> 4) * 8;
        int r0 = (wv & 1) * 16;
        int c0 = (wv >> 1) * 16;
        const f16* Ap = &Ao[(r0 + l15) * LDK + kg];
        const f16* Bp = &Wt[(c0 + l15) * LDK + kg];
        f32x4 acc2 = {0.f, 0.f, 0.f, 0.f};
#pragma unroll
        for (int ks = 0; ks < K / 32; ++ks) {
            int k0 = ks * 32;
            half8 a  = *(const half8*)(Ap + k0);
            half8 bb = *(const half8*)(Bp + k0);
            acc2 = __builtin_amdgcn_mfma_f32_16x16x32_f16(a, bb, acc2, 0, 0, 0);
        }
        int orow = r0 + (lane >> 4) * 4;
#pragma unroll
        for (int i = 0; i < 4; ++i) {
            long row = tileBase + orow + i;
            if (row >= N_NODES) break;
            float dv = dinv[row];
            hs_out[row * EMB + c0 + l15] = __float2half(dv * acc2[i]);
        }
    }
}

// ---------- pooling helpers ----------
__device__ inline int f2ord(float x) {
    int bb = __float_as_int(x);
    return bb >= 0 ? bb : (bb ^ 0x7fffffff);
}
__device__ inline float ord2f(int k) {
    return __int_as_float(k >= 0 ? k : (k ^ 0x7fffffff));
}

// ---------- FUSED agg(layer 3) + pool: 4-chain interleaved agg ----------
__global__ __launch_bounds__(512) void agg_pool_k(const __half* __restrict__ hs_in,
                                                  const int2* __restrict__ csr,
                                                  const int* __restrict__ row_start,
                                                  const int* __restrict__ row_end,
                                                  const float* __restrict__ dinv,
                                                  const float* __restrict__ b,
                                                  const int* __restrict__ batch,
                                                  int* gmax, float* gsum, int* cnt) {
    __shared__ __align__(16) int2 Ecsr[ECAP];
    __shared__ float Ho[BM * EMB];
    __shared__ int PadB[BM + 1], RealB[BM];
    __shared__ int realTot;
    int tid = threadIdx.x;
    int wv = tid >> 6, lane = tid & 63;
    long tileBase = (long)blockIdx.x * BM;

    STAGE_PADDED();
    __syncthreads();

    const char* hsb = (const char*)hs_in + (size_t)(lane * 2);
    float acc[4];
    int bs[4], nb[4];
#pragma unroll
    for (int i = 0; i < 4; ++i) {
        long node = tileBase + wv * 4 + i;
        bool valid = node < N_NODES;
        acc[i] = valid ? __half2float(hs_in[node * EMB + lane]) : 0.f;
        int idx = wv * 4 + i;
        bs[i] = PadB[idx];
        nb[i] = staged ? ((PadB[idx + 1] - PadB[idx]) >> 3) : 0;
    }
    if (staged) {
        agg_chains4(hsb, Ecsr, bs, nb, acc);
    } else {
#pragma unroll
        for (int i = 0; i < 4; ++i) {
            long node = tileBase + wv * 4 + i;
            if (node >= N_NODES) break;
            acc[i] = agg_row_g(hsb, csr, row_start[node], row_end[node], acc[i]);
        }
    }
    {
        float bl = b[lane];
#pragma unroll
        for (int i = 0; i < 4; ++i) {
            long node = tileBase + wv * 4 + i;
            if (node >= N_NODES) break;
            Ho[(wv * 4 + i) * EMB + lane] = tanhf(dinv[node] * acc[i] + bl);
        }
    }
    __syncthreads();
    if (wv < BM / POOL_CHUNK) {   // waves 0-1 pool the two 16-node chunks
        long start = tileBase + wv * POOL_CHUNK;
        if (start >= N_NODES) return;   // 50000 % 16 == 0 -> full chunks when valid
        int bsel = (lane < POOL_CHUNK) ? batch[start + lane] : 0;
        float v[POOL_CHUNK];
#pragma unroll
        for (int i = 0; i < POOL_CHUNK; ++i)
            v[i] = Ho[(wv * POOL_CHUNK + i) * EMB + lane];
        int curg = __shfl(bsel, 0);
        float mx = -INFINITY, sm = 0.f;
        int ct = 0;
#pragma unroll
        for (int i = 0; i < POOL_CHUNK; ++i) {
            int g = __shfl(bsel, i);
            if (g != curg) {
                atomicMax(&gmax[curg * EMB + lane], f2ord(mx));
                atomicAdd(&gsum[curg * EMB + lane], sm);
                if (lane == 0) atomicAdd(&cnt[curg], ct);
                curg = g; mx = -INFINITY; sm = 0.f; ct = 0;
            }
            mx = fmaxf(mx, v[i]);
            sm += v[i];
            ++ct;
        }
        atomicMax(&gmax[curg * EMB + lane], f2ord(mx));
        atomicAdd(&gsum[curg * EMB + lane], sm);
        if (lane == 0) atomicAdd(&cnt[curg], ct);
    }
}

__global__ void final_k(const int* __restrict__ gmax, const float* __restrict__ gsum,
                        const int* __restrict__ cnt, const float* __restrict__ Wout,
                        const float* __restrict__ bout, float* __restrict__ out) {
    int g = threadIdx.x;
    if (g >= N_GRAPHS) return;
    float c = fmaxf((float)cnt[g], 1.0f);
    float acc = bout[0];
    for (int ch = 0; ch < EMB; ++ch) {
        acc += ord2f(gmax[g * EMB + ch]) * Wout[ch]
             + (gsum[g * EMB + ch] / c) * Wout[EMB + ch];
    }
    out[g] = acc;
}

extern "C" void kernel_launch(void* const* d_in, const int* in_sizes, int n_in,
                              void* d_out, int out_size, void* d_ws, size_t ws_size,
                              hipStream_t stream) {
    const float* x         = (const float*)d_in[0];
    const int*   edge_idx  = (const int*)d_in[1];
    const float* edge_attr = (const float*)d_in[2];
    const int*   batch     = (const int*)d_in[3];
    const float* W0 = (const float*)d_in[4];
    const float* b0 = (const float*)d_in[5];
    const float* W1 = (const float*)d_in[6];
    const float* b1 = (const float*)d_in[7];
    const float* W2 = (const float*)d_in[8];
    const float* b2 = (const float*)d_in[9];
    const float* W3 = (const float*)d_in[10];
    const float* b3 = (const float*)d_in[11];
    const float* Wout = (const float*)d_in[12];
    const float* bout = (const float*)d_in[13];
    float* out = (float*)d_out;

    const int* src = edge_idx;            // edge_index[0]
    const int* dst = edge_idx + N_EDGES;  // edge_index[1]

    // workspace layout (~33 MB)
    char* ws = (char*)d_ws;
    float*  dinv      = (float*)ws;  ws += (size_t)N_NODES * sizeof(float);
    unsigned long long* cnt64 = (unsigned long long*)ws;
    ws += (size_t)N_NODES * CPAD64 * sizeof(unsigned long long);
    int*    row_start = (int*)ws;    ws += (size_t)N_NODES * sizeof(int);
    int*    row_end   = (int*)ws;    ws += (size_t)N_NODES * sizeof(int);
    int*    slot_in   = (int*)ws;    ws += (size_t)N_EDGES * sizeof(int);
    int*    total     = (int*)ws;    ws += 4 * sizeof(int);  // keep 16B alignment
    int2*   csr       = (int2*)ws;   ws += (size_t)N_EDGES * sizeof(int2);
    __half* bufL      = (__half*)ws; ws += (size_t)N_NODES * EMB * sizeof(__half);
    __half* bufM      = (__half*)ws; ws += (size_t)N_NODES * EMB * sizeof(__half);
    int*    gmax      = (int*)ws;    ws += N_GRAPHS * EMB * sizeof(int);
    float*  gsum      = (float*)ws;  ws += N_GRAPHS * EMB * sizeof(float);
    int*    cnt       = (int*)ws;    ws += N_GRAPHS * sizeof(int);

    const int nodeB  = (N_NODES + 255) / 256;
    const int edgeB  = (N_EDGES + 255) / 256;
    const int gemm0B = (N_NODES + 63) / 64;      // 782 blocks, 64-node tiles
    const int fuseB  = (N_NODES + BM - 1) / BM;  // 1563 blocks, 32-node tiles
    const int initB  = (N_NODES * CPAD64 + 255) / 256;

    // CSR precompute (norm fully folded; count+weighted-degree via ONE 64b atomic)
    init_k<<<initB, 256, 0, stream>>>(cnt64, total, gmax, gsum, cnt);
    hist_k<<<edgeB, 256, 0, stream>>>(dst, edge_attr, cnt64, slot_in);
    alloc_k<<<nodeB, 256, 0, stream>>>(cnt64, row_start, row_end, total, dinv);
    scatter_k<<<edgeB, 256, 0, stream>>>(src, dst, edge_attr, slot_in, row_start, csr);

    // layer pipeline: gemm0, then fused agg_l+gemm_{l+1}, then fused agg3+pool
    gemm_k<IN_CH, false><<<gemm0B, 256, 0, stream>>>(x, W0, dinv, bufL);
    agg_gemm_k<<<fuseB, 512, 0, stream>>>(bufL, csr, row_start, row_end, dinv, b0, W1, bufM);
    agg_gemm_k<<<fuseB, 512, 0, stream>>>(bufM, csr, row_start, row_end, dinv, b1, W2, bufL);
    agg_gemm_k<<<fuseB, 512, 0, stream>>>(bufL, csr, row_start, row_end, dinv, b2, W3, bufM);
    agg_pool_k<<<fuseB, 512, 0, stream>>>(bufM, csr, row_start, row_end, dinv, b3,
                                          batch, gmax, gsum, cnt);
    final_k<<<1, 64, 0, stream>>>(gmax, gsum, cnt, Wout, bout, out);
}

// Round 13
// 305.779 us; speedup vs baseline: 4.5720x; 1.1347x over previous
//
#include <hip/hip_runtime.h>
#include <hip/hip_fp16.h>
#include <math.h>
#include <limits.h>

#define N_NODES 50000
#define N_EDGES 800000
#define N_GRAPHS 64
#define IN_CH 128
#define EMB 64
#define POOL_CHUNK 16   // 50000 = 16 * 3125 exactly
#define CPAD64 16       // one 128B line per node: single u64 = (count<<44) | wsum_fx24
#define CNT_SHIFT 44
#define FX_SCALE 16777216.0f   // 2^24 fixed-point for edge weights (w in [0,1))
#define BM 32           // fused-kernel tile: 32 nodes (half of a 64-node alloc group)
#define ECAP 2048       // LDS csr stage capacity (mean 512/tile -> never hit for random)

typedef _Float16 f16;
typedef __attribute__((ext_vector_type(8))) _Float16 half8;
typedef __attribute__((ext_vector_type(4))) float f32x4;

// ---------- init: packed counters=0, total=0, pool accumulators ----------
__global__ void init_k(unsigned long long* cnt64, int* total, int* gmax,
                       float* gsum, int* cnt) {
    int i = blockIdx.x * blockDim.x + threadIdx.x;
    if (i < N_NODES * CPAD64) cnt64[i] = 0ULL;
    if (i == 0) *total = 0;
    if (i < N_GRAPHS * EMB) { gmax[i] = INT_MIN; gsum[i] = 0.f; }
    if (i < N_GRAPHS) cnt[i] = 0;
}

// ---------- histogram: ONE packed 64-bit atomic per edge ----------
__global__ void hist_k(const int* __restrict__ dst, const float* __restrict__ w,
                       unsigned long long* cnt64, int* __restrict__ slot_in) {
    int e = blockIdx.x * blockDim.x + threadIdx.x;
    if (e >= N_EDGES) return;
    unsigned long long fx = (unsigned long long)(w[e] * FX_SCALE + 0.5f);
    unsigned long long old = atomicAdd(&cnt64[(size_t)dst[e] * CPAD64],
                                       (1ULL << CNT_SHIFT) | fx);
    slot_in[e] = (int)(old >> CNT_SHIFT);
}

// ---------- CSR range allocation: wave-scan + one atomic per wave; dinv folded ----
// One atomicAdd per 64-node group + ascending prefix => every BM-aligned tile
// owns a CONTIGUOUS csr range (fused kernels stage it in LDS).
__global__ void alloc_k(const unsigned long long* __restrict__ cnt64,
                        int* __restrict__ row_start, int* __restrict__ row_end,
                        int* total, float* __restrict__ dinv) {
    int i = blockIdx.x * blockDim.x + threadIdx.x;
    int lane = threadIdx.x & 63;
    unsigned long long v = (i < N_NODES) ? cnt64[(size_t)i * CPAD64] : 0ULL;
    int c = (int)(v >> CNT_SHIFT);
    int inc = c;
    for (int off = 1; off < 64; off <<= 1) {
        int t = __shfl_up(inc, off);
        if (lane >= off) inc += t;
    }
    int base;
    if (lane == 63) base = atomicAdd(total, inc);
    base = __shfl(base, 63);
    int excl = base + inc - c;
    if (i < N_NODES) {
        row_start[i] = excl;
        row_end[i] = excl + c;
        float degw = (float)(v & ((1ULL << CNT_SHIFT) - 1)) * (1.0f / FX_SCALE);
        float d = 1.0f + degw;  // + self-loop weight 1
        dinv[i] = d > 0.f ? rsqrtf(d) : 0.f;
    }
}

// ---------- scatter edges into CSR slots (atomic-free) ----------
// csr.x = src * EMB * 2 (BYTE offset into fp16 feature buffer); csr.y = raw w.
__global__ void scatter_k(const int* __restrict__ src, const int* __restrict__ dst,
                          const float* __restrict__ w, const int* __restrict__ slot_in,
                          const int* __restrict__ row_start, int2* __restrict__ csr) {
    int e = blockIdx.x * blockDim.x + threadIdx.x;
    if (e >= N_EDGES) return;
    int d = dst[e];
    int slot = row_start[d] + slot_in[e];
    csr[slot] = make_int2(src[e] * (EMB * 2), __float_as_int(w[e]));
}

// ---------- agg inner: acc += sum over edge array slice (lane = channel) ----------
// earr is the LDS-staged slice (ds_read broadcast) or global csr (fallback).
// 16-gather batches first (avg degree ~16 -> most nodes finish in ONE batch,
// halving dependent round-trips vs 8-batches), then 8, then scalar tail.
__device__ __forceinline__ float agg_row(const char* hsb, const int2* earr,
                                         int e, int end, float acc) {
    for (; e + 15 < end; e += 16) {
        int2 r[16];
#pragma unroll
        for (int j = 0; j < 16; ++j) r[j] = earr[e + j];
        __half v[16];
#pragma unroll
        for (int j = 0; j < 16; ++j) v[j] = *(const __half*)(hsb + (unsigned)r[j].x);
#pragma unroll
        for (int j = 0; j < 16; ++j) acc += __int_as_float(r[j].y) * __half2float(v[j]);
    }
    if (e + 7 < end) {
        int2 r[8];
#pragma unroll
        for (int j = 0; j < 8; ++j) r[j] = earr[e + j];
        __half v[8];
#pragma unroll
        for (int j = 0; j < 8; ++j) v[j] = *(const __half*)(hsb + (unsigned)r[j].x);
#pragma unroll
        for (int j = 0; j < 8; ++j) acc += __int_as_float(r[j].y) * __half2float(v[j]);
        e += 8;
    }
    for (; e < end; ++e) {
        int2 r = earr[e];
        acc += __int_as_float(r.y) * __half2float(*(const __half*)(hsb + (unsigned)r.x));
    }
    return acc;
}

// ---------- hs = dinv * (A @ W) via MFMA 16x16x32 f16 (layer 0, fp32 input) ----------
template<int K, bool HALF_IN>
__global__ __launch_bounds__(256) void gemm_k(const void* __restrict__ A_,
                                              const float* __restrict__ W,
                                              const float* __restrict__ dinv,
                                              __half* __restrict__ out) {
    constexpr int LDK = K + 8;
    __shared__ __align__(16) f16 Al[64 * LDK];
    __shared__ __align__(16) f16 Wt[EMB * LDK];   // Wt[n][k]
    int tid = threadIdx.x;
    long rowBase = (long)blockIdx.x * 64;
    int validRows = (int)min((long)64, (long)N_NODES - rowBase);

    if constexpr (HALF_IN) {
        const __half* Ah = (const __half*)A_ + rowBase * K;
        constexpr int CH = K / 8;
        for (int i = tid; i < validRows * CH; i += 256) {
            int r = i / CH, c = i % CH;
            uint4 v = *(const uint4*)(Ah + (long)r * K + c * 8);
            *(uint4*)&Al[r * LDK + c * 8] = v;
        }
    } else {
        const float* Af = (const float*)A_;
        constexpr int CH = K / 4;
        for (int i = tid; i < validRows * CH; i += 256) {
            int r = i / CH, c = i % CH;
            float4 v = *(const float4*)(Af + (rowBase + r) * K + c * 4);
            __half2 p0 = __floats2half2_rn(v.x, v.y);
            __half2 p1 = __floats2half2_rn(v.z, v.w);
            uint2 u = make_uint2(*(unsigned int*)&p0, *(unsigned int*)&p1);
            *(uint2*)&Al[r * LDK + c * 4] = u;
        }
    }
    {   // zero-fill invalid rows (last block only)
        constexpr int CZ = K / 8;
        for (int i = tid + validRows * CZ; i < 64 * CZ; i += 256) {
            int r = i / CZ, c = i % CZ;
            *(uint4*)&Al[r * LDK + c * 8] = make_uint4(0, 0, 0, 0);
        }
    }
    {   // stage W transposed fp32 -> fp16
        const float4* Wg = (const float4*)W;
        for (int i = tid; i < K * (EMB / 4); i += 256) {
            int k = i >> 4, nq = i & 15;
            float4 v = Wg[i];
            Wt[(4 * nq + 0) * LDK + k] = (f16)v.x;
            Wt[(4 * nq + 1) * LDK + k] = (f16)v.y;
            Wt[(4 * nq + 2) * LDK + k] = (f16)v.z;
            Wt[(4 * nq + 3) * LDK + k] = (f16)v.w;
        }
    }
    __syncthreads();

    int wv = tid >> 6, lane = tid & 63;
    int l15 = lane & 15, kg = (lane >> 4) * 8;
    const f16* Ap = &Al[(wv * 16 + l15) * LDK + kg];
    const f16* Bp = &Wt[l15 * LDK + kg];
    f32x4 acc0 = {0.f, 0.f, 0.f, 0.f};
    f32x4 acc1 = acc0, acc2 = acc0, acc3 = acc0;
#pragma unroll
    for (int ks = 0; ks < K / 32; ++ks) {
        int k0 = ks * 32;
        half8 a  = *(const half8*)(Ap + k0);
        half8 b0 = *(const half8*)(Bp + k0);
        half8 b1 = *(const half8*)(Bp + 16 * LDK + k0);
        half8 b2 = *(const half8*)(Bp + 32 * LDK + k0);
        half8 b3 = *(const half8*)(Bp + 48 * LDK + k0);
        acc0 = __builtin_amdgcn_mfma_f32_16x16x32_f16(a, b0, acc0, 0, 0, 0);
        acc1 = __builtin_amdgcn_mfma_f32_16x16x32_f16(a, b1, acc1, 0, 0, 0);
        acc2 = __builtin_amdgcn_mfma_f32_16x16x32_f16(a, b2, acc2, 0, 0, 0);
        acc3 = __builtin_amdgcn_mfma_f32_16x16x32_f16(a, b3, acc3, 0, 0, 0);
    }
    int orow = wv * 16 + (lane >> 4) * 4;
#pragma unroll
    for (int i = 0; i < 4; ++i) {
        long row = rowBase + orow + i;
        if (row >= N_NODES) break;
        float dv = dinv[row];
        __half* op = &out[row * EMB + l15];
        op[0]  = __float2half(dv * acc0[i]);
        op[16] = __float2half(dv * acc1[i]);
        op[32] = __float2half(dv * acc2[i]);
        op[48] = __float2half(dv * acc3[i]);
    }
}

// ---------- FUSED agg(layer l) + gemm(layer l+1), BM=32 tile, LDS-staged csr ----------
// The tile's csr slice [row_start[first], row_end[last]) is CONTIGUOUS (see
// alloc_k) -> one coalesced block load into LDS. Agg then never touches global
// csr: ds_read (broadcast) for (src,w), gathers are the only long-latency ops.
__global__ __launch_bounds__(512) void agg_gemm_k(const __half* __restrict__ hs_in,
                                                  const int2* __restrict__ csr,
                                                  const int* __restrict__ row_start,
                                                  const int* __restrict__ row_end,
                                                  const float* __restrict__ dinv,
                                                  const float* __restrict__ b,
                                                  const float* __restrict__ W,
                                                  __half* __restrict__ hs_out) {
    constexpr int K = EMB;       // 64
    constexpr int LDK = K + 8;   // 72
    __shared__ __align__(16) int2 Ecsr[ECAP];
    __shared__ __align__(16) f16 Ao[BM * LDK];
    __shared__ __align__(16) f16 Wt[EMB * LDK];
    int tid = threadIdx.x;
    int wv = tid >> 6, lane = tid & 63;
    long tileBase = (long)blockIdx.x * BM;
    int validRows = (int)min((long)BM, (long)N_NODES - tileBase);

    {   // stage W transposed fp32 -> fp16 (Wt[n][k])
        const float4* Wg = (const float4*)W;
        for (int i = tid; i < K * (EMB / 4); i += 512) {
            int k = i >> 4, nq = i & 15;
            float4 v = Wg[i];
            Wt[(4 * nq + 0) * LDK + k] = (f16)v.x;
            Wt[(4 * nq + 1) * LDK + k] = (f16)v.y;
            Wt[(4 * nq + 2) * LDK + k] = (f16)v.z;
            Wt[(4 * nq + 3) * LDK + k] = (f16)v.w;
        }
    }
    int eBeg = row_start[tileBase];
    int eTot = row_end[tileBase + validRows - 1] - eBeg;
    bool staged = (eTot <= ECAP);
    if (staged) {   // coalesced bulk load of the tile's whole csr slice
        for (int i = tid; i < eTot; i += 512) Ecsr[i] = csr[eBeg + i];
    }
    __syncthreads();
    {   // phase 1: aggregation, 4 nodes per wave, lane = channel
        const char* hsb = (const char*)hs_in + (size_t)(lane * 2);
        float bl = b[lane];
        for (int i = 0; i < 4; ++i) {
            long node = tileBase + wv * 4 + i;
            if (node >= N_NODES) break;
            float di = dinv[node];
            float acc = __half2float(hs_in[node * EMB + lane]);   // self term
            int rs = row_start[node], re = row_end[node];
            if (staged) acc = agg_row(hsb, Ecsr, rs - eBeg, re - eBeg, acc);
            else        acc = agg_row(hsb, csr, rs, re, acc);
            float o = tanhf(di * acc + bl);
            Ao[(wv * 4 + i) * LDK + lane] = (f16)o;
        }
    }
    if (validRows < BM) {   // zero-fill invalid rows (tail block only)
        for (int i = tid; i < (BM - validRows) * (K / 8); i += 512) {
            int r = validRows + i / (K / 8), c = i % (K / 8);
            *(uint4*)&Ao[r * LDK + c * 8] = make_uint4(0, 0, 0, 0);
        }
    }
    __syncthreads();
    {   // phase 2: MFMA 32x64 @ 64x64; one 16x16 tile per wave
        int l15 = lane & 15, kg = (lane >> 4) * 8;
        int r0 = (wv & 1) * 16;
        int c0 = (wv >> 1) * 16;
        const f16* Ap = &Ao[(r0 + l15) * LDK + kg];
        const f16* Bp = &Wt[(c0 + l15) * LDK + kg];
        f32x4 acc = {0.f, 0.f, 0.f, 0.f};
#pragma unroll
        for (int ks = 0; ks < K / 32; ++ks) {
            int k0 = ks * 32;
            half8 a  = *(const half8*)(Ap + k0);
            half8 bb = *(const half8*)(Bp + k0);
            acc = __builtin_amdgcn_mfma_f32_16x16x32_f16(a, bb, acc, 0, 0, 0);
        }
        int orow = r0 + (lane >> 4) * 4;
#pragma unroll
        for (int i = 0; i < 4; ++i) {
            long row = tileBase + orow + i;
            if (row >= N_NODES) break;
            float dv = dinv[row];
            hs_out[row * EMB + c0 + l15] = __float2half(dv * acc[i]);
        }
    }
}

// ---------- pooling helpers ----------
__device__ inline int f2ord(float x) {
    int bb = __float_as_int(x);
    return bb >= 0 ? bb : (bb ^ 0x7fffffff);
}
__device__ inline float ord2f(int k) {
    return __int_as_float(k >= 0 ? k : (k ^ 0x7fffffff));
}

// ---------- FUSED agg(layer 3) + pool, BM=32 tile, LDS-staged csr ----------
__global__ __launch_bounds__(512) void agg_pool_k(const __half* __restrict__ hs_in,
                                                  const int2* __restrict__ csr,
                                                  const int* __restrict__ row_start,
                                                  const int* __restrict__ row_end,
                                                  const float* __restrict__ dinv,
                                                  const float* __restrict__ b,
                                                  const int* __restrict__ batch,
                                                  int* gmax, float* gsum, int* cnt) {
    __shared__ __align__(16) int2 Ecsr[ECAP];
    __shared__ float Ho[BM * EMB];
    int tid = threadIdx.x;
    int wv = tid >> 6, lane = tid & 63;
    long tileBase = (long)blockIdx.x * BM;
    int validRows = (int)min((long)BM, (long)N_NODES - tileBase);

    int eBeg = row_start[tileBase];
    int eTot = row_end[tileBase + validRows - 1] - eBeg;
    bool staged = (eTot <= ECAP);
    if (staged) {
        for (int i = tid; i < eTot; i += 512) Ecsr[i] = csr[eBeg + i];
    }
    __syncthreads();
    {
        const char* hsb = (const char*)hs_in + (size_t)(lane * 2);
        float bl = b[lane];
        for (int i = 0; i < 4; ++i) {
            long node = tileBase + wv * 4 + i;
            if (node >= N_NODES) break;
            float di = dinv[node];
            float acc = __half2float(hs_in[node * EMB + lane]);
            int rs = row_start[node], re = row_end[node];
            if (staged) acc = agg_row(hsb, Ecsr, rs - eBeg, re - eBeg, acc);
            else        acc = agg_row(hsb, csr, rs, re, acc);
            Ho[(wv * 4 + i) * EMB + lane] = tanhf(di * acc + bl);
        }
    }
    __syncthreads();
    if (wv < BM / POOL_CHUNK) {   // waves 0-1 pool the two 16-node chunks
        long start = tileBase + wv * POOL_CHUNK;
        if (start >= N_NODES) return;   // 50000 % 16 == 0 -> full chunks when valid
        int bsel = (lane < POOL_CHUNK) ? batch[start + lane] : 0;
        float v[POOL_CHUNK];
#pragma unroll
        for (int i = 0; i < POOL_CHUNK; ++i)
            v[i] = Ho[(wv * POOL_CHUNK + i) * EMB + lane];
        int curg = __shfl(bsel, 0);
        float mx = -INFINITY, sm = 0.f;
        int ct = 0;
#pragma unroll
        for (int i = 0; i < POOL_CHUNK; ++i) {
            int g = __shfl(bsel, i);
            if (g != curg) {
                atomicMax(&gmax[curg * EMB + lane], f2ord(mx));
                atomicAdd(&gsum[curg * EMB + lane], sm);
                if (lane == 0) atomicAdd(&cnt[curg], ct);
                curg = g; mx = -INFINITY; sm = 0.f; ct = 0;
            }
            mx = fmaxf(mx, v[i]);
            sm += v[i];
            ++ct;
        }
        atomicMax(&gmax[curg * EMB + lane], f2ord(mx));
        atomicAdd(&gsum[curg * EMB + lane], sm);
        if (lane == 0) atomicAdd(&cnt[curg], ct);
    }
}

__global__ void final_k(const int* __restrict__ gmax, const float* __restrict__ gsum,
                        const int* __restrict__ cnt, const float* __restrict__ Wout,
                        const float* __restrict__ bout, float* __restrict__ out) {
    int g = threadIdx.x;
    if (g >= N_GRAPHS) return;
    float c = fmaxf((float)cnt[g], 1.0f);
    float acc = bout[0];
    for (int ch = 0; ch < EMB; ++ch) {
        acc += ord2f(gmax[g * EMB + ch]) * Wout[ch]
             + (gsum[g * EMB + ch] / c) * Wout[EMB + ch];
    }
    out[g] = acc;
}

extern "C" void kernel_launch(void* const* d_in, const int* in_sizes, int n_in,
                              void* d_out, int out_size, void* d_ws, size_t ws_size,
                              hipStream_t stream) {
    const float* x         = (const float*)d_in[0];
    const int*   edge_idx  = (const int*)d_in[1];
    const float* edge_attr = (const float*)d_in[2];
    const int*   batch     = (const int*)d_in[3];
    const float* W0 = (const float*)d_in[4];
    const float* b0 = (const float*)d_in[5];
    const float* W1 = (const float*)d_in[6];
    const float* b1 = (const float*)d_in[7];
    const float* W2 = (const float*)d_in[8];
    const float* b2 = (const float*)d_in[9];
    const float* W3 = (const float*)d_in[10];
    const float* b3 = (const float*)d_in[11];
    const float* Wout = (const float*)d_in[12];
    const float* bout = (const float*)d_in[13];
    float* out = (float*)d_out;

    const int* src = edge_idx;            // edge_index[0]
    const int* dst = edge_idx + N_EDGES;  // edge_index[1]

    // workspace layout (~33 MB)
    char* ws = (char*)d_ws;
    float*  dinv      = (float*)ws;  ws += (size_t)N_NODES * sizeof(float);
    unsigned long long* cnt64 = (unsigned long long*)ws;
    ws += (size_t)N_NODES * CPAD64 * sizeof(unsigned long long);
    int*    row_start = (int*)ws;    ws += (size_t)N_NODES * sizeof(int);
    int*    row_end   = (int*)ws;    ws += (size_t)N_NODES * sizeof(int);
    int*    slot_in   = (int*)ws;    ws += (size_t)N_EDGES * sizeof(int);
    int*    total     = (int*)ws;    ws += 4 * sizeof(int);  // keep 16B alignment
    int2*   csr       = (int2*)ws;   ws += (size_t)N_EDGES * sizeof(int2);
    __half* bufL      = (__half*)ws; ws += (size_t)N_NODES * EMB * sizeof(__half);
    __half* bufM      = (__half*)ws; ws += (size_t)N_NODES * EMB * sizeof(__half);
    int*    gmax      = (int*)ws;    ws += N_GRAPHS * EMB * sizeof(int);
    float*  gsum      = (float*)ws;  ws += N_GRAPHS * EMB * sizeof(float);
    int*    cnt       = (int*)ws;    ws += N_GRAPHS * sizeof(int);

    const int nodeB  = (N_NODES + 255) / 256;
    const int edgeB  = (N_EDGES + 255) / 256;
    const int gemm0B = (N_NODES + 63) / 64;      // 782 blocks, 64-node tiles
    const int fuseB  = (N_NODES + BM - 1) / BM;  // 1563 blocks, 32-node tiles
    const int initB  = (N_NODES * CPAD64 + 255) / 256;

    // CSR precompute (norm fully folded; count+weighted-degree via ONE 64b atomic)
    init_k<<<initB, 256, 0, stream>>>(cnt64, total, gmax, gsum, cnt);
    hist_k<<<edgeB, 256, 0, stream>>>(dst, edge_attr, cnt64, slot_in);
    alloc_k<<<nodeB, 256, 0, stream>>>(cnt64, row_start, row_end, total, dinv);
    scatter_k<<<edgeB, 256, 0, stream>>>(src, dst, edge_attr, slot_in, row_start, csr);

    // layer pipeline: gemm0, then fused agg_l+gemm_{l+1}, then fused agg3+pool
    gemm_k<IN_CH, false><<<gemm0B, 256, 0, stream>>>(x, W0, dinv, bufL);
    agg_gemm_k<<<fuseB, 512, 0, stream>>>(bufL, csr, row_start, row_end, dinv, b0, W1, bufM);
    agg_gemm_k<<<fuseB, 512, 0, stream>>>(bufM, csr, row_start, row_end, dinv, b1, W2, bufL);
    agg_gemm_k<<<fuseB, 512, 0, stream>>>(bufL, csr, row_start, row_end, dinv, b2, W3, bufM);
    agg_pool_k<<<fuseB, 512, 0, stream>>>(bufM, csr, row_start, row_end, dinv, b3,
                                          batch, gmax, gsum, cnt);
    final_k<<<1, 64, 0, stream>>>(gmax, gsum, cnt, Wout, bout, out);
}